// Round 7
// baseline (299.250 us; speedup 1.0000x reference)
//
#include <hip/hip_runtime.h>

// ChebyKANLayer: y[t,o] = bias[o] + sum_k A[t,k]*B[k,o], K=8192, k=i*8+(d-1), d=1..8.
// R7: K-split x2 (grid 1024, 4 blocks/CU -> 4 waves/SIMD, double the occupancy of R6);
// halves merged with hw f32 atomics (deterministic: fp add commutes, 2 adders/address).
// out zeroed inside prep. Lean R5-style inline A-gen (low VGPR). B via global_load_lds,
// conflict-free [k-chunk][col] LDS layout, LDS double-buffer.

typedef __bf16 bf16;
typedef __bf16 bf16x8 __attribute__((ext_vector_type(8)));
typedef float f32x2 __attribute__((ext_vector_type(2)));
typedef float f32x4 __attribute__((ext_vector_type(4)));
typedef float f32x16 __attribute__((ext_vector_type(16)));

__device__ __forceinline__ void g2lds16(const void* g, void* l) {
  __builtin_amdgcn_global_load_lds(
      (const __attribute__((address_space(1))) unsigned int*)g,
      (__attribute__((address_space(3))) unsigned int*)l, 16, 0, 0);
}

__device__ __forceinline__ float fast_tanh(float a) {
  float e = __expf(a + a);
  return 1.f - 2.f * __builtin_amdgcn_rcpf(e + 1.f);   // saturating, NaN-free
}

// ---- fused prep: blocks [0,1024) build Bt + bias partials; [1024,9216) tanh + zero out.
// Bt entry (nb, s, c, col) = bf16(C[i=s*8+c][o=nb*128+col][d=1..8]).
// th[r][(i>>1)+(i&1)*512] = tanh(x[r][i]).  bias_p[p][o] = sum_{i in p-block} C[i][o][0].
__global__ __launch_bounds__(256)
void cheby_prep(const float* __restrict__ x, const float* __restrict__ C,
                bf16* __restrict__ Bt, float* __restrict__ bias_p,
                float* __restrict__ th, float* __restrict__ out) {
  const int bid = blockIdx.x, tid = threadIdx.x;
  if (bid >= 1024) {                               // ---- tanh branch: one token row
    const int r = bid - 1024;
    f32x4 v = *(const f32x4*)(x + (size_t)r * 1024 + tid * 4);
    f32x4 t;
    #pragma unroll
    for (int j = 0; j < 4; ++j) t[j] = fast_tanh(v[j]);
    *(f32x2*)(th + (size_t)r * 1024 + tid * 2)       = (f32x2){t.x, t.z};  // even i
    *(f32x2*)(th + (size_t)r * 1024 + 512 + tid * 2) = (f32x2){t.y, t.w};  // odd i
    *(f32x4*)(out + (size_t)r * 1024 + tid * 4) = (f32x4){0.f, 0.f, 0.f, 0.f};
    return;
  }
  __shared__ float tile[32][292];
  const int i0 = (bid >> 5) * 32, o0 = (bid & 31) * 32;
  {
    const int r = tid >> 3, seg = tid & 7;
    const float* src = C + (size_t)(i0 + r) * 9216 + (size_t)o0 * 9 + seg * 36;
    float* dst = &tile[r][seg * 36];
    #pragma unroll
    for (int v = 0; v < 9; ++v) *(f32x4*)(dst + v * 4) = *(const f32x4*)(src + v * 4);
  }
  __syncthreads();
  #pragma unroll
  for (int j = 0; j < 4; ++j) {
    int e = tid + 256 * j;
    int il = e >> 5, ol = e & 31;
    int i = i0 + il, o = o0 + ol;
    bf16x8 v;
    #pragma unroll
    for (int d = 0; d < 8; ++d) v[d] = (bf16)tile[il][ol * 9 + 1 + d];
    size_t idx16 = ((size_t)((o >> 7) * 128 + (i >> 3)) * 8 + (i & 7)) * 128 + (o & 127);
    *(bf16x8*)&Bt[idx16 * 8] = v;
  }
  if (tid < 32) {
    float s = 0.f;
    #pragma unroll
    for (int i = 0; i < 32; ++i) s += tile[i][tid * 9];
    bias_p[(size_t)(bid >> 5) * 1024 + o0 + tid] = s;   // partial, no atomics
  }
}

// ---- fused basis-gen + GEMM: block 128x128xK/2, 256 thr (2x2 waves, wave 64x64).
// grid 1024 = mb(64) x kh(2) x nb(8) -> 4 blocks/CU.
__global__ __launch_bounds__(256, 4)
void cheby_gemm(const float* __restrict__ th, const bf16* __restrict__ Bt,
                const float* __restrict__ bias_p, float* __restrict__ out) {
  __shared__ bf16 Bs[2][8192];                     // 2 x 16 KB: [c 0..7][col 0..127][8]

  const int tid  = threadIdx.x;
  const int lane = tid & 63, w = tid >> 6;
  const int wm = w >> 1, wn = w & 1;
  const int nb = blockIdx.x & 7;                   // bid&7 -> XCD: Bt slice L2-resident
  const int kh = (blockIdx.x >> 3) & 1;            // K-half
  const int mb = blockIdx.x >> 4;
  const int t0 = mb * 128, o0 = nb * 128;
  const int ml = lane & 31, h = lane >> 5;

  const float* xr0 = th + (size_t)(t0 + wm * 64 + ml) * 1024 + h * 512;
  const float* xr1 = xr0 + 32 * 1024;
  const bf16* btw = Bt + ((size_t)nb * 128 * 1024 + (size_t)w * 256 + lane) * 8;

  const int sbeg = kh * 64, send = sbeg + 64;

  f32x16 acc[2][2];
  #pragma unroll
  for (int a = 0; a < 2; ++a)
    #pragma unroll
    for (int b = 0; b < 2; ++b)
      #pragma unroll
      for (int r = 0; r < 16; ++r) acc[a][b][r] = 0.f;

  f32x4 xv0 = *(const f32x4*)(xr0 + sbeg * 4);
  f32x4 xv1 = *(const f32x4*)(xr1 + sbeg * 4);

  #pragma unroll
  for (int b = 0; b < 4; ++b)                      // prologue: stage sbeg -> buf 0
    g2lds16(btw + (size_t)sbeg * 8192 + (size_t)b * 64 * 8,
            &Bs[0][(w * 256 + b * 64) * 8]);

  #pragma unroll 1
  for (int s = sbeg; s < send; ++s) {
    const int bi = (s - sbeg) & 1;
    __syncthreads();                               // Bs[bi] landed; Bs[bi^1] free
    if (s < send - 1) {
      const bf16* g = btw + (size_t)(s + 1) * 8192;
      #pragma unroll
      for (int b = 0; b < 4; ++b)
        g2lds16(g + (size_t)b * 64 * 8, &Bs[bi ^ 1][(w * 256 + b * 64) * 8]);
    }

    f32x4 sd0 = xv0, sd1 = xv1;
    if (s < send - 1) {                            // prefetch next stage's seeds
      xv0 = *(const f32x4*)(xr0 + (s + 1) * 4);
      xv1 = *(const f32x4*)(xr1 + (s + 1) * 4);
    }

    bf16x8 afr[2][4];
    #pragma unroll
    for (int ks = 0; ks < 4; ++ks) {               // row-paired chains -> v_pk_fma_f32
      f32x2 t  = {sd0[ks], sd1[ks]};
      f32x2 t2 = t + t;
      f32x2 prev = {1.f, 1.f}, cur = t;
      #pragma unroll
      for (int j = 0; j < 8; ++j) {
        afr[0][ks][j] = (bf16)cur.x;
        afr[1][ks][j] = (bf16)cur.y;
        f32x2 nx = t2 * cur - prev;
        prev = cur; cur = nx;
      }
    }

    #pragma unroll
    for (int ks = 0; ks < 4; ++ks) {
      const int ce = ((ks * 2 + h) * 128 + wn * 64 + ml) * 8;   // half-wave contiguous
      bf16x8 b0 = *(const bf16x8*)&Bs[bi][ce];
      bf16x8 b1 = *(const bf16x8*)&Bs[bi][ce + 32 * 8];
      acc[0][0] = __builtin_amdgcn_mfma_f32_32x32x16_bf16(afr[0][ks], b0, acc[0][0], 0, 0, 0);
      acc[0][1] = __builtin_amdgcn_mfma_f32_32x32x16_bf16(afr[0][ks], b1, acc[0][1], 0, 0, 0);
      acc[1][0] = __builtin_amdgcn_mfma_f32_32x32x16_bf16(afr[1][ks], b0, acc[1][0], 0, 0, 0);
      acc[1][1] = __builtin_amdgcn_mfma_f32_32x32x16_bf16(afr[1][ks], b1, acc[1][1], 0, 0, 0);
    }
  }

  // epilogue: kh0 adds bias; halves merge via hw f32 atomics (out pre-zeroed in prep).
  // C/D layout col=lane&31, row=(reg&3)+8*(reg>>2)+4*h (m74/m101-verified).
  const int c0 = o0 + wn * 64 + ml;
  float bv0 = 0.f, bv1 = 0.f;
  if (kh == 0) {
    #pragma unroll
    for (int p = 0; p < 32; ++p) {
      bv0 += bias_p[(size_t)p * 1024 + c0];
      bv1 += bias_p[(size_t)p * 1024 + c0 + 32];
    }
  }
  #pragma unroll
  for (int mt = 0; mt < 2; ++mt)
    #pragma unroll
    for (int r = 0; r < 16; ++r) {
      int row = t0 + wm * 64 + mt * 32 + (r & 3) + 8 * (r >> 2) + 4 * h;
      float* po = out + (size_t)row * 1024 + c0;
      unsafeAtomicAdd(&po[0],  acc[mt][0][r] + bv0);
      unsafeAtomicAdd(&po[32], acc[mt][1][r] + bv1);
    }
}

// ---- fallback (ws too small) — correct, slow, should never run
__global__ __launch_bounds__(256)
void cheby_naive(const float* __restrict__ x, const float* __restrict__ C,
                 float* __restrict__ out) {
  const int t = blockIdx.x, tid = threadIdx.x;
  float acc[4] = {0.f, 0.f, 0.f, 0.f};
  for (int i = 0; i < 1024; ++i) {
    float th = tanhf(x[(size_t)t * 1024 + i]);
    float T[9]; T[0] = 1.f; T[1] = th;
    #pragma unroll
    for (int d = 2; d < 9; ++d) T[d] = 2.f * th * T[d - 1] - T[d - 2];
    #pragma unroll
    for (int j = 0; j < 4; ++j) {
      const float* cp = &C[((size_t)i * 1024 + tid + j * 256) * 9];
      float s = 0.f;
      #pragma unroll
      for (int d = 0; d < 9; ++d) s += T[d] * cp[d];
      acc[j] += s;
    }
  }
  #pragma unroll
  for (int j = 0; j < 4; ++j) out[(size_t)t * 1024 + tid + j * 256] = acc[j];
}

extern "C" void kernel_launch(void* const* d_in, const int* in_sizes, int n_in,
                              void* d_out, int out_size, void* d_ws, size_t ws_size,
                              hipStream_t stream) {
  (void)in_sizes; (void)n_in; (void)out_size;
  const float* x = (const float*)d_in[0];
  const float* C = (const float*)d_in[1];
  float* out = (float*)d_out;

  const size_t bt_bytes = (size_t)8 * 128 * 1024 * 8 * sizeof(bf16);  // 16.78 MB
  const size_t bp_bytes = (size_t)32 * 1024 * sizeof(float);          // 128 KB
  const size_t th_bytes = (size_t)8192 * 1024 * sizeof(float);        // 33.55 MB

  if (ws_size >= bt_bytes + bp_bytes + th_bytes) {
    bf16*  Bt     = (bf16*)d_ws;
    float* bias_p = (float*)((char*)d_ws + bt_bytes);
    float* th     = (float*)((char*)d_ws + bt_bytes + bp_bytes);
    cheby_prep<<<9216, 256, 0, stream>>>(x, C, Bt, bias_p, th, out);
    cheby_gemm<<<1024, 256, 0, stream>>>(th, Bt, bias_p, out);
  } else {
    cheby_naive<<<8192, 256, 0, stream>>>(x, C, out);
  }
}

// Round 8
// 294.087 us; speedup vs baseline: 1.0176x; 1.0176x over previous
//
#include <hip/hip_runtime.h>

// ChebyKANLayer: y[t,o] = bias[o] + sum_k A[t,k]*B[k,o], K=8192, k=i*8+(d-1), d=1..8.
// R8: barrier-free, LDS-free GEMM. One wave per block (64x64 tile), grid 2048
// (mb128 x wn2 x nb8), 8 waves/CU. B-fragments loaded straight from Bt (L2-resident
// per-XCD slice) into VGPRs -- no __shared__, no __syncthreads, so the compiler can
// use fine-grained vmcnt overlap (the thing the 2-barrier K-loop structurally forbids).
// A-fragments generated in registers from precomputed tanh seeds (thw, gather layout).

typedef __bf16 bf16;
typedef __bf16 bf16x8 __attribute__((ext_vector_type(8)));
typedef float f32x2 __attribute__((ext_vector_type(2)));
typedef float f32x4 __attribute__((ext_vector_type(4)));
typedef float f32x16 __attribute__((ext_vector_type(16)));

__device__ __forceinline__ float fast_tanh(float a) {
  float e = __expf(a + a);
  return 1.f - 2.f * __builtin_amdgcn_rcpf(e + 1.f);   // saturating, NaN-free
}

// ---- fused prep ----
// blocks [0,1024): Bt + bias partials.
//   Bt entry (nb, s, c, col) = bf16(C[i=s*8+c][o=nb*128+col][d=1..8]), 16B units:
//   idx16 = ((nb*128+s)*8 + c)*128 + col.
// blocks [1024,1280): thw gather layout:
//   thw[((mb*128+s)*64 + lane)*8 + mt*4 + ks] = tanh(x[mb*64+mt*32+(lane&31)][s*8+2ks+(lane>>5)])
//   -> per (wave-stage): 2 coalesced dwordx4 per lane.
__global__ __launch_bounds__(256)
void cheby_prep(const float* __restrict__ x, const float* __restrict__ C,
                bf16* __restrict__ Bt, float* __restrict__ bias_p,
                float* __restrict__ thw) {
  const int bid = blockIdx.x, tid = threadIdx.x;
  if (bid >= 1024) {                               // ---- thw branch
    const int b2 = bid - 1024;
    const int mbg = b2 >> 1;                       // 64-row group [0,128)
    const int sh = (b2 & 1) * 64;                  // stage half [sh, sh+64)
    __shared__ float lt[64][65];
    for (int c8 = 0; c8 < 8; ++c8) {               // 8 tiles of 64 i-cols (8 stages each)
      const int i0 = sh * 8 + c8 * 64;
      __syncthreads();
      #pragma unroll
      for (int p = 0; p < 4; ++p) {                // coalesced read + tanh
        int idx = tid + p * 256;
        int row = idx >> 4, sg = idx & 15;
        f32x4 v = *(const f32x4*)(x + (size_t)(mbg * 64 + row) * 1024 + i0 + sg * 4);
        #pragma unroll
        for (int j = 0; j < 4; ++j) lt[row][sg * 4 + j] = fast_tanh(v[j]);
      }
      __syncthreads();
      #pragma unroll
      for (int half = 0; half < 2; ++half) {       // coalesced gather-layout write
        int slot = tid + half * 256;
        int js = slot >> 6, ln = slot & 63;
        int ml = ln & 31, h = ln >> 5;
        f32x4 v0, v1;
        #pragma unroll
        for (int ks = 0; ks < 4; ++ks) {
          v0[ks] = lt[ml][js * 8 + 2 * ks + h];
          v1[ks] = lt[32 + ml][js * 8 + 2 * ks + h];
        }
        size_t off = ((size_t)(mbg * 128 + sh + c8 * 8 + js) * 64 + ln) * 8;
        *(f32x4*)(thw + off)     = v0;
        *(f32x4*)(thw + off + 4) = v1;
      }
    }
    return;
  }
  // ---- Bt + bias branch
  __shared__ float tile[32][292];
  const int i0 = (bid >> 5) * 32, o0 = (bid & 31) * 32;
  {
    const int r = tid >> 3, seg = tid & 7;
    const float* src = C + (size_t)(i0 + r) * 9216 + (size_t)o0 * 9 + seg * 36;
    float* dst = &tile[r][seg * 36];
    #pragma unroll
    for (int v = 0; v < 9; ++v) *(f32x4*)(dst + v * 4) = *(const f32x4*)(src + v * 4);
  }
  __syncthreads();
  #pragma unroll
  for (int j = 0; j < 4; ++j) {
    int e = tid + 256 * j;
    int il = e >> 5, ol = e & 31;
    int i = i0 + il, o = o0 + ol;
    bf16x8 v;
    #pragma unroll
    for (int d = 0; d < 8; ++d) v[d] = (bf16)tile[il][ol * 9 + 1 + d];
    size_t idx16 = ((size_t)((o >> 7) * 128 + (i >> 3)) * 8 + (i & 7)) * 128 + (o & 127);
    *(bf16x8*)&Bt[idx16 * 8] = v;
  }
  if (tid < 32) {
    float s = 0.f;
    #pragma unroll
    for (int i = 0; i < 32; ++i) s += tile[i][tid * 9];
    bias_p[(size_t)(bid >> 5) * 1024 + o0 + tid] = s;   // partial, no atomics
  }
}

// ---- barrier-free GEMM: 1 wave/block, 64x64 tile, full K ----
__global__ __launch_bounds__(64, 2)
void cheby_gemm(const float* __restrict__ thw, const bf16* __restrict__ Bt,
                const float* __restrict__ bias_p, float* __restrict__ out) {
  const int lane = threadIdx.x;
  const int ml = lane & 31, h = lane >> 5;
  const int nb = blockIdx.x & 7;                   // bid&7 -> XCD: Bt slice L2-resident
  const int wn = (blockIdx.x >> 3) & 1;
  const int mb = blockIdx.x >> 4;                  // [0,128)
  const int t0 = mb * 64, o0 = nb * 128 + wn * 64;

  // B lane pointer (elements): entry idx16 = ((nb*128+s)*8 + c)*128 + col
  // offset(s,ks,nt) = s*8192 + ks*2048 + nt*256 elements
  const bf16* btl = Bt + (((size_t)nb * 128 * 8 + h) * 128 + (size_t)wn * 64 + ml) * 8;
  const float* sp = thw + ((size_t)mb * 128 * 64 + lane) * 8;   // + s*512 per stage

  f32x16 acc[2][2];
  #pragma unroll
  for (int a = 0; a < 2; ++a)
    #pragma unroll
    for (int b = 0; b < 2; ++b)
      #pragma unroll
      for (int r = 0; r < 16; ++r) acc[a][b][r] = 0.f;

  bf16x8 bA[4][2], bB[4][2];
  f32x4 s0a, s0b, s1a, s1b;

  // prologue: stage 0 -> bA / s0
  #pragma unroll
  for (int ks = 0; ks < 4; ++ks)
    #pragma unroll
    for (int nt = 0; nt < 2; ++nt)
      bA[ks][nt] = *(const bf16x8*)(btl + ks * 2048 + nt * 256);
  s0a = *(const f32x4*)(sp);
  s0b = *(const f32x4*)(sp + 4);

  // half-stage: load stage `sload` into (bld,sla,slb) if doload; gen+MFMA stage from (bcur,sca,scb)
  auto halfstage = [&](int sload, bf16x8 (&bld)[4][2], f32x4& sla, f32x4& slb,
                       bf16x8 (&bcur)[4][2], f32x4 sca, f32x4 scb, bool doload) {
    if (doload) {
      const bf16* g = btl + (size_t)sload * 8192;
      #pragma unroll
      for (int ks = 0; ks < 4; ++ks)
        #pragma unroll
        for (int nt = 0; nt < 2; ++nt)
          bld[ks][nt] = *(const bf16x8*)(g + ks * 2048 + nt * 256);
      sla = *(const f32x4*)(sp + (size_t)sload * 512);
      slb = *(const f32x4*)(sp + (size_t)sload * 512 + 4);
    }
    bf16x8 afr[2][4];
    #pragma unroll
    for (int ks = 0; ks < 4; ++ks) {               // row(mt)-paired chains -> pk_fma
      f32x2 t  = {sca[ks], scb[ks]};
      f32x2 t2 = t + t;
      f32x2 prev = {1.f, 1.f}, cur = t;
      #pragma unroll
      for (int j = 0; j < 8; ++j) {
        afr[0][ks][j] = (bf16)cur.x;
        afr[1][ks][j] = (bf16)cur.y;
        f32x2 nx = t2 * cur - prev;
        prev = cur; cur = nx;
      }
    }
    #pragma unroll
    for (int ks = 0; ks < 4; ++ks) {
      acc[0][0] = __builtin_amdgcn_mfma_f32_32x32x16_bf16(afr[0][ks], bcur[ks][0], acc[0][0], 0, 0, 0);
      acc[0][1] = __builtin_amdgcn_mfma_f32_32x32x16_bf16(afr[0][ks], bcur[ks][1], acc[0][1], 0, 0, 0);
      acc[1][0] = __builtin_amdgcn_mfma_f32_32x32x16_bf16(afr[1][ks], bcur[ks][0], acc[1][0], 0, 0, 0);
      acc[1][1] = __builtin_amdgcn_mfma_f32_32x32x16_bf16(afr[1][ks], bcur[ks][1], acc[1][1], 0, 0, 0);
    }
  };

  #pragma unroll 1
  for (int s = 0; s < 128; s += 2) {
    halfstage(s + 1, bB, s1a, s1b, bA, s0a, s0b, true);       // load s+1, compute s
    halfstage(s + 2, bA, s0a, s0b, bB, s1a, s1b, s < 126);    // load s+2, compute s+1
  }

  // epilogue: 32x32 C/D layout col=lane&31, row=(reg&3)+8*(reg>>2)+4*h (m74/m101)
  float bv0 = 0.f, bv1 = 0.f;
  #pragma unroll
  for (int p = 0; p < 32; ++p) {
    bv0 += bias_p[(size_t)p * 1024 + o0 + ml];
    bv1 += bias_p[(size_t)p * 1024 + o0 + 32 + ml];
  }
  #pragma unroll
  for (int mt = 0; mt < 2; ++mt)
    #pragma unroll
    for (int r = 0; r < 16; ++r) {
      int row = t0 + mt * 32 + (r & 3) + 8 * (r >> 2) + 4 * h;
      float* po = out + (size_t)row * 1024 + o0 + ml;
      po[0]  = acc[mt][0][r] + bv0;
      po[32] = acc[mt][1][r] + bv1;
    }
}

// ---- fallback (ws too small) — correct, slow, should never run
__global__ __launch_bounds__(256)
void cheby_naive(const float* __restrict__ x, const float* __restrict__ C,
                 float* __restrict__ out) {
  const int t = blockIdx.x, tid = threadIdx.x;
  float acc[4] = {0.f, 0.f, 0.f, 0.f};
  for (int i = 0; i < 1024; ++i) {
    float th = tanhf(x[(size_t)t * 1024 + i]);
    float T[9]; T[0] = 1.f; T[1] = th;
    #pragma unroll
    for (int d = 2; d < 9; ++d) T[d] = 2.f * th * T[d - 1] - T[d - 2];
    #pragma unroll
    for (int j = 0; j < 4; ++j) {
      const float* cp = &C[((size_t)i * 1024 + tid + j * 256) * 9];
      float s = 0.f;
      #pragma unroll
      for (int d = 0; d < 9; ++d) s += T[d] * cp[d];
      acc[j] += s;
    }
  }
  #pragma unroll
  for (int j = 0; j < 4; ++j) out[(size_t)t * 1024 + tid + j * 256] = acc[j];
}

extern "C" void kernel_launch(void* const* d_in, const int* in_sizes, int n_in,
                              void* d_out, int out_size, void* d_ws, size_t ws_size,
                              hipStream_t stream) {
  (void)in_sizes; (void)n_in; (void)out_size;
  const float* x = (const float*)d_in[0];
  const float* C = (const float*)d_in[1];
  float* out = (float*)d_out;

  const size_t bt_bytes = (size_t)8 * 128 * 1024 * 8 * sizeof(bf16);  // 16.78 MB
  const size_t bp_bytes = (size_t)32 * 1024 * sizeof(float);          // 128 KB
  const size_t th_bytes = (size_t)8192 * 1024 * sizeof(float);        // 33.55 MB

  if (ws_size >= bt_bytes + bp_bytes + th_bytes) {
    bf16*  Bt     = (bf16*)d_ws;
    float* bias_p = (float*)((char*)d_ws + bt_bytes);
    float* thw    = (float*)((char*)d_ws + bt_bytes + bp_bytes);
    cheby_prep<<<1280, 256, 0, stream>>>(x, C, Bt, bias_p, thw);
    cheby_gemm<<<2048, 64, 0, stream>>>(thw, Bt, bias_p, out);
  } else {
    cheby_naive<<<8192, 256, 0, stream>>>(x, C, out);
  }
}

// Round 9
// 290.174 us; speedup vs baseline: 1.0313x; 1.0135x over previous
//
#include <hip/hip_runtime.h>

// ChebyKANLayer: y[t,o] = bias[o] + sum_k A[t,k]*B[k,o], K=8192, k=i*8+(d-1), d=1..8.
// R9: barrier-free LDS-free GEMM (R8 skeleton) with
//  (a) stride-2 packed Chebyshev: T_{d+2} = (4t^2-2) T_d - T_{d-2}; odd/even subchains
//      as f32x2 -> v_pk_fma_f32 + pairable bf16 converts (~13 inst/chain vs ~24);
//  (b) fixed-depth pipeline: seeds prefetched 2 stages ahead (4-slot reg rotation),
//      B 1 stage ahead (2-slot), loads issued seeds-first -> gen never drains fresh B;
//  (c) 256-thr blocks = 4 independent waves (no __syncthreads anywhere).

typedef __bf16 bf16;
typedef __bf16 bf16x8 __attribute__((ext_vector_type(8)));
typedef float f32x2 __attribute__((ext_vector_type(2)));
typedef float f32x4 __attribute__((ext_vector_type(4)));
typedef float f32x16 __attribute__((ext_vector_type(16)));

__device__ __forceinline__ float fast_tanh(float a) {
  float e = __expf(a + a);
  return 1.f - 2.f * __builtin_amdgcn_rcpf(e + 1.f);   // saturating, NaN-free
}

// ---- fused prep (R6-proven): blocks [0,1024) build Bt + bias partials;
// [1024,9216) tanh rows into even/odd-half layout th[r][(i>>1)+(i&1)*512].
// Bt 16B-unit idx16 = ((nb*128 + s)*8 + c)*128 + col,  s=i>>3, c=i&7, nb=o>>7, col=o&127.
__global__ __launch_bounds__(256)
void cheby_prep(const float* __restrict__ x, const float* __restrict__ C,
                bf16* __restrict__ Bt, float* __restrict__ bias_p,
                float* __restrict__ th) {
  const int bid = blockIdx.x, tid = threadIdx.x;
  if (bid >= 1024) {                               // ---- tanh branch: one token row
    const int r = bid - 1024;
    f32x4 v = *(const f32x4*)(x + (size_t)r * 1024 + tid * 4);
    f32x4 t;
    #pragma unroll
    for (int j = 0; j < 4; ++j) t[j] = fast_tanh(v[j]);
    *(f32x2*)(th + (size_t)r * 1024 + tid * 2)       = (f32x2){t.x, t.z};  // even i
    *(f32x2*)(th + (size_t)r * 1024 + 512 + tid * 2) = (f32x2){t.y, t.w};  // odd i
    return;
  }
  __shared__ float tile[32][292];
  const int i0 = (bid >> 5) * 32, o0 = (bid & 31) * 32;
  {
    const int r = tid >> 3, seg = tid & 7;
    const float* src = C + (size_t)(i0 + r) * 9216 + (size_t)o0 * 9 + seg * 36;
    float* dst = &tile[r][seg * 36];
    #pragma unroll
    for (int v = 0; v < 9; ++v) *(f32x4*)(dst + v * 4) = *(const f32x4*)(src + v * 4);
  }
  __syncthreads();
  #pragma unroll
  for (int j = 0; j < 4; ++j) {
    int e = tid + 256 * j;
    int il = e >> 5, ol = e & 31;
    int i = i0 + il, o = o0 + ol;
    bf16x8 v;
    #pragma unroll
    for (int d = 0; d < 8; ++d) v[d] = (bf16)tile[il][ol * 9 + 1 + d];
    size_t idx16 = ((size_t)((o >> 7) * 128 + (i >> 3)) * 8 + (i & 7)) * 128 + (o & 127);
    *(bf16x8*)&Bt[idx16 * 8] = v;
  }
  if (tid < 32) {
    float s = 0.f;
    #pragma unroll
    for (int i = 0; i < 32; ++i) s += tile[i][tid * 9];
    bias_p[(size_t)(bid >> 5) * 1024 + o0 + tid] = s;   // partial, no atomics
  }
}

// ---- barrier-free GEMM: 256 thr = 4 independent waves (2x2 over a 128x128 block tile),
// wave tile 64x64, grid 512 (mb64 x nb8). Full K per wave.
__global__ __launch_bounds__(256, 2)
void cheby_gemm(const float* __restrict__ th, const bf16* __restrict__ Bt,
                const float* __restrict__ bias_p, float* __restrict__ out) {
  const int tid  = threadIdx.x;
  const int lane = tid & 63, w = tid >> 6;
  const int ml = lane & 31, h = lane >> 5;
  const int nb = blockIdx.x & 7;                   // bid&7 -> XCD: Bt slice L2-resident
  const int mb = blockIdx.x >> 3;                  // [0,64)
  const int wn = w & 1, wm = w >> 1;
  const int t0 = mb * 128 + wm * 64;
  const int o0 = nb * 128 + wn * 64;

  // B lane base: idx16 = ((nb*128+s)*8 + c)*128 + col ; offsets (elem): s*8192, ks*2048, nt*256
  const bf16* btl = Bt + (((size_t)nb * 1024 + h) * 128 + (size_t)wn * 64 + ml) * 8;
  // seeds: f32x4 at sp + s*4 = tanh at i = s*8 + 2ks + h  (R5 even/odd-half layout)
  const float* sp0 = th + (size_t)(t0 + ml) * 1024 + h * 512;         // mt=0 row
  const float* sp1 = sp0 + 32 * 1024;                                 // mt=1 row

  f32x16 acc[2][2];
  #pragma unroll
  for (int a = 0; a < 2; ++a)
    #pragma unroll
    for (int b = 0; b < 2; ++b)
      #pragma unroll
      for (int r = 0; r < 16; ++r) acc[a][b][r] = 0.f;

  f32x4  sa[4], sb[4];        // seed slots, stage s -> slot s&3 (2-ahead prefetch)
  bf16x8 bfr[2][4][2];        // B slots,    stage s -> slot s&1 (1-ahead prefetch)

  // prologue: seeds(0),(1); B(0)
  sa[0] = *(const f32x4*)(sp0);     sb[0] = *(const f32x4*)(sp1);
  sa[1] = *(const f32x4*)(sp0 + 4); sb[1] = *(const f32x4*)(sp1 + 4);
  #pragma unroll
  for (int ks = 0; ks < 4; ++ks) {
    bfr[0][ks][0] = *(const bf16x8*)(btl + ks * 2048);
    bfr[0][ks][1] = *(const bf16x8*)(btl + ks * 2048 + 256);
  }

  #pragma unroll 1
  for (int s4 = 0; s4 < 128; s4 += 4) {
    #pragma unroll
    for (int u = 0; u < 4; ++u) {
      const int s = s4 + u;
      // 1. seeds for s+2 (slot (u+2)&3) -- issued FIRST
      {
        int sl = s + 2; if (sl > 127) sl = 127;
        sa[(u + 2) & 3] = *(const f32x4*)(sp0 + sl * 4);
        sb[(u + 2) & 3] = *(const f32x4*)(sp1 + sl * 4);
      }
      // 2. B for s+1 (slot (u+1)&1)
      {
        int bl = s + 1; if (bl > 127) bl = 127;
        const bf16* g = btl + (size_t)bl * 8192;
        #pragma unroll
        for (int ks = 0; ks < 4; ++ks) {
          bfr[(u + 1) & 1][ks][0] = *(const bf16x8*)(g + ks * 2048);
          bfr[(u + 1) & 1][ks][1] = *(const bf16x8*)(g + ks * 2048 + 256);
        }
      }
      // 3. gen A-frags from seeds slot u (loaded 2 stages ago): stride-2 packed chains
      bf16x8 afr[2][4];
      #pragma unroll
      for (int r = 0; r < 2; ++r) {
        const f32x4 sd = r ? sb[u & 3] : sa[u & 3];
        #pragma unroll
        for (int ks = 0; ks < 4; ++ks) {
          const float t  = sd[ks];
          const float T2 = __builtin_fmaf(t + t, t, -1.f);   // T_2 = 2t^2-1
          const float c2 = T2 + T2;                          // 2*T_2 = 4t^2-2
          const f32x2 c2v = {c2, c2};
          f32x2 pm1 = {t, 1.f};                              // (T_-1, T_0)
          f32x2 p   = {t, T2};                               // (T_1, T_2)
          #pragma unroll
          for (int j2 = 0; j2 < 4; ++j2) {                   // dword j2 = (T_{2j2+1}, T_{2j2+2})
            afr[r][ks][2 * j2]     = (bf16)p.x;
            afr[r][ks][2 * j2 + 1] = (bf16)p.y;
            f32x2 pn = c2v * p - pm1;                        // pk_fma: next (odd, even) pair
            pm1 = p; p = pn;
          }
        }
      }
      // 4. MFMA on B slot u&1 (loaded 1 stage ago)
      #pragma unroll
      for (int ks = 0; ks < 4; ++ks) {
        acc[0][0] = __builtin_amdgcn_mfma_f32_32x32x16_bf16(afr[0][ks], bfr[u & 1][ks][0], acc[0][0], 0, 0, 0);
        acc[0][1] = __builtin_amdgcn_mfma_f32_32x32x16_bf16(afr[0][ks], bfr[u & 1][ks][1], acc[0][1], 0, 0, 0);
        acc[1][0] = __builtin_amdgcn_mfma_f32_32x32x16_bf16(afr[1][ks], bfr[u & 1][ks][0], acc[1][0], 0, 0, 0);
        acc[1][1] = __builtin_amdgcn_mfma_f32_32x32x16_bf16(afr[1][ks], bfr[u & 1][ks][1], acc[1][1], 0, 0, 0);
      }
    }
  }

  // epilogue: bias from partials; 32x32 C/D layout col=lane&31, row=(reg&3)+8*(reg>>2)+4*h
  float bv0 = 0.f, bv1 = 0.f;
  #pragma unroll
  for (int p = 0; p < 32; ++p) {
    bv0 += bias_p[(size_t)p * 1024 + o0 + ml];
    bv1 += bias_p[(size_t)p * 1024 + o0 + 32 + ml];
  }
  #pragma unroll
  for (int mt = 0; mt < 2; ++mt)
    #pragma unroll
    for (int r = 0; r < 16; ++r) {
      int row = t0 + mt * 32 + (r & 3) + 8 * (r >> 2) + 4 * h;
      float* po = out + (size_t)row * 1024 + o0 + ml;
      po[0]  = acc[mt][0][r] + bv0;
      po[32] = acc[mt][1][r] + bv1;
    }
}

// ---- fallback (ws too small) — correct, slow, should never run
__global__ __launch_bounds__(256)
void cheby_naive(const float* __restrict__ x, const float* __restrict__ C,
                 float* __restrict__ out) {
  const int t = blockIdx.x, tid = threadIdx.x;
  float acc[4] = {0.f, 0.f, 0.f, 0.f};
  for (int i = 0; i < 1024; ++i) {
    float th = tanhf(x[(size_t)t * 1024 + i]);
    float T[9]; T[0] = 1.f; T[1] = th;
    #pragma unroll
    for (int d = 2; d < 9; ++d) T[d] = 2.f * th * T[d - 1] - T[d - 2];
    #pragma unroll
    for (int j = 0; j < 4; ++j) {
      const float* cp = &C[((size_t)i * 1024 + tid + j * 256) * 9];
      float s = 0.f;
      #pragma unroll
      for (int d = 0; d < 9; ++d) s += T[d] * cp[d];
      acc[j] += s;
    }
  }
  #pragma unroll
  for (int j = 0; j < 4; ++j) out[(size_t)t * 1024 + tid + j * 256] = acc[j];
}

extern "C" void kernel_launch(void* const* d_in, const int* in_sizes, int n_in,
                              void* d_out, int out_size, void* d_ws, size_t ws_size,
                              hipStream_t stream) {
  (void)in_sizes; (void)n_in; (void)out_size;
  const float* x = (const float*)d_in[0];
  const float* C = (const float*)d_in[1];
  float* out = (float*)d_out;

  const size_t bt_bytes = (size_t)8 * 128 * 1024 * 8 * sizeof(bf16);  // 16.78 MB
  const size_t bp_bytes = (size_t)32 * 1024 * sizeof(float);          // 128 KB
  const size_t th_bytes = (size_t)8192 * 1024 * sizeof(float);        // 33.55 MB

  if (ws_size >= bt_bytes + bp_bytes + th_bytes) {
    bf16*  Bt     = (bf16*)d_ws;
    float* bias_p = (float*)((char*)d_ws + bt_bytes);
    float* th     = (float*)((char*)d_ws + bt_bytes + bp_bytes);
    cheby_prep<<<9216, 256, 0, stream>>>(x, C, Bt, bias_p, th);
    cheby_gemm<<<512, 256, 0, stream>>>(th, Bt, bias_p, out);
  } else {
    cheby_naive<<<8192, 256, 0, stream>>>(x, C, out);
  }
}